// Round 7
// baseline (270.773 us; speedup 1.0000x reference)
//
#include <hip/hip_runtime.h>
#include <math.h>

// Problem constants (from reference)
#define BG    100        // graphs
#define NPG   500        // nodes per graph (layer 1)
#define FD    128        // feature dim (F_IN == H == 128)
#define EE    600000     // edges
#define EPG   6000       // edges per graph (contiguous, never cross graphs)
#define NN    50000      // total nodes layer 1
#define K1    250
#define K2    125
#define K3    63
#define CAP   64         // max in-degree capacity

typedef short v8s __attribute__((ext_vector_type(8)));
typedef float v4f __attribute__((ext_vector_type(4)));

// XCD-aligned swizzle (R9 win)
__device__ __forceinline__ int swz(int p, int N) {
    int j = p & 7, i = p >> 3;
    int chunk = N >> 3, rem = N & 7;
    int mj = j < rem ? j : rem;
    return j * chunk + mj + i;
}

// float -> bf16 RNE bits
__device__ __forceinline__ unsigned short f2bf(float f) {
    unsigned int u = __float_as_uint(f);
    unsigned int r = (u + 0x7FFFu + ((u >> 16) & 1u)) >> 16;
    return (unsigned short)r;
}
__device__ __forceinline__ float bf2f(unsigned short b) {
    return __uint_as_float(((unsigned int)b) << 16);
}

// ---------------- merged prep: blocks [0,BG) build layer-1 CSR (LDS counters);
// blocks [BG, BG+96) convert W -> Wt_hi/Wt_lo bf16 in MFMA-staging order:
// o = [layer][kt=k>>5][t=n>>4][quad=(k>>3)&3][l15=n&15][q=k&7]  (k = [Wl | Wr] rows)
__global__ __launch_bounds__(1024) void prep_fill_kernel(
        const int* __restrict__ ei, int* __restrict__ deg, int* __restrict__ col,
        const float* __restrict__ Wl1, const float* __restrict__ Wr1,
        const float* __restrict__ Wl2, const float* __restrict__ Wr2,
        const float* __restrict__ Wl3, const float* __restrict__ Wr3,
        unsigned short* __restrict__ wt_hi, unsigned short* __restrict__ wt_lo) {
    __shared__ int lcnt[NPG];
    int tid = threadIdx.x;
    if (blockIdx.x < BG) {
        int b = swz(blockIdx.x, BG);
        for (int i = tid; i < NPG; i += 1024) lcnt[i] = 0;
        __syncthreads();
        for (int e0 = tid; e0 < EPG; e0 += 1024) {
            int e = b * EPG + e0;
            int d = ei[EE + e];
            int pos = atomicAdd(&lcnt[d - b * NPG], 1);
            if (pos < CAP) col[(long long)d * CAP + pos] = ei[e];
        }
        __syncthreads();
        for (int i = tid; i < NPG; i += 1024) deg[b * NPG + i] = lcnt[i];
    } else {
        int id = (blockIdx.x - BG) * 1024 + tid;          // 3*256*128 = 98304
        if (id >= 3 * 256 * 128) return;
        int layer = id >> 15, rem = id & 32767;
        int k = rem >> 7, n = rem & 127;
        const float* Wl = layer == 0 ? Wl1 : (layer == 1 ? Wl2 : Wl3);
        const float* Wr = layer == 0 ? Wr1 : (layer == 1 ? Wr2 : Wr3);
        float w = (k < 128) ? Wl[k * 128 + n] : Wr[(k - 128) * 128 + n];
        unsigned short hi = f2bf(w);
        unsigned short lo = f2bf(w - bf2f(hi));
        long long o = (long long)layer * 32768
                    + (long long)(k >> 5) * 4096          // kt
                    + (long long)(n >> 4) * 512           // t
                    + (long long)((k >> 3) & 3) * 128     // quad
                    + (long long)(n & 15) * 8             // l15
                    + (k & 7);                            // q
        wt_hi[o] = hi;
        wt_lo[o] = lo;
    }
}

// ------- fused gather + SAGE GEMM (128-row tile, 8 waves, bf16x2-split MFMA) -------
// Phase 1 (gather): cooperative 32-lanes-per-row aggregation of the block's 128
// rows, 16 rows per group staged by all 512 threads into mslab[16][132] (float4-
// aligned pad); wave rg (whose fragment rows are exactly group rg) copies its 32
// A-values to registers. Same j-ascending chain per column as the standalone
// gather kernel -> bit-identical mean values; rows >= M produce zeros (d=0).
// Phase 2 (GEMM): identical to R6 — B slab per kt staged lane-contiguously from
// the pre-permuted wt (conflict-free write+read), kt<4 A from macc registers
// (fully unrolled so macc stays in VGPRs), kt>=4 A direct from x.
// Removes the mean global round-trip (51 MB) and 3 gather dispatches.
__global__ __launch_bounds__(512) void sage_gemm_fused_kernel(
        const int* __restrict__ deg, const int* __restrict__ col,
        const float* __restrict__ x,
        const unsigned short* __restrict__ wt_hi, const unsigned short* __restrict__ wt_lo,
        const float* __restrict__ bl, const float* __restrict__ pw,
        float* __restrict__ hout, float* __restrict__ score, int M, int NB) {
    __shared__ unsigned short Bh[4096], Bl[4096];   // one kt-slab: [t][quad][l15][q]
    __shared__ float mslab[16 * 132];               // 16 gathered rows, padded
    __shared__ float spart[128 * 16];
    __shared__ float snrmp[16];
    int tid  = threadIdx.x;
    int wave = tid >> 6, lane = tid & 63;
    int quad = lane >> 4, l15 = lane & 15;
    int row0 = swz(blockIdx.x, NB) * 128;

    v4f acc[8];
#pragma unroll
    for (int t = 0; t < 8; t++) acc[t] = (v4f){0.f, 0.f, 0.f, 0.f};

    if (tid < 16) {
        float s = 0.f;
#pragma unroll
        for (int t = 0; t < 8; t++) { float p = pw[t * 16 + tid]; s += p * p; }
        snrmp[tid] = s;
    }

    int growA = row0 + 16 * wave + l15; if (growA > M - 1) growA = M - 1;

    // ---- phase 1: fused gather-aggregate into macc registers ----
    float macc[32];
    {
        int rlocal = tid >> 5;      // 0..15 row within group
        int sub    = tid & 31;      // float4 column slot
        for (int rg = 0; rg < 8; ++rg) {
            int row = row0 + rg * 16 + rlocal;
            int d = (row < M) ? deg[row] : 0;
            if (d > CAP) d = CAP;
            const int* cp = col + (long long)row * CAP;
            float ax = 0.0f, ay = 0.0f, az = 0.0f, aw = 0.0f;
            int j = 0;
            for (; j + 8 <= d; j += 8) {
                float4 v0 = ((const float4*)(x + (long long)cp[j]     * FD))[sub];
                float4 v1 = ((const float4*)(x + (long long)cp[j + 1] * FD))[sub];
                float4 v2 = ((const float4*)(x + (long long)cp[j + 2] * FD))[sub];
                float4 v3 = ((const float4*)(x + (long long)cp[j + 3] * FD))[sub];
                float4 v4 = ((const float4*)(x + (long long)cp[j + 4] * FD))[sub];
                float4 v5 = ((const float4*)(x + (long long)cp[j + 5] * FD))[sub];
                float4 v6 = ((const float4*)(x + (long long)cp[j + 6] * FD))[sub];
                float4 v7 = ((const float4*)(x + (long long)cp[j + 7] * FD))[sub];
                ax += v0.x; ay += v0.y; az += v0.z; aw += v0.w;
                ax += v1.x; ay += v1.y; az += v1.z; aw += v1.w;
                ax += v2.x; ay += v2.y; az += v2.z; aw += v2.w;
                ax += v3.x; ay += v3.y; az += v3.z; aw += v3.w;
                ax += v4.x; ay += v4.y; az += v4.z; aw += v4.w;
                ax += v5.x; ay += v5.y; az += v5.z; aw += v5.w;
                ax += v6.x; ay += v6.y; az += v6.z; aw += v6.w;
                ax += v7.x; ay += v7.y; az += v7.z; aw += v7.w;
            }
            for (; j + 4 <= d; j += 4) {
                float4 v0 = ((const float4*)(x + (long long)cp[j]     * FD))[sub];
                float4 v1 = ((const float4*)(x + (long long)cp[j + 1] * FD))[sub];
                float4 v2 = ((const float4*)(x + (long long)cp[j + 2] * FD))[sub];
                float4 v3 = ((const float4*)(x + (long long)cp[j + 3] * FD))[sub];
                ax += v0.x; ay += v0.y; az += v0.z; aw += v0.w;
                ax += v1.x; ay += v1.y; az += v1.z; aw += v1.w;
                ax += v2.x; ay += v2.y; az += v2.z; aw += v2.w;
                ax += v3.x; ay += v3.y; az += v3.z; aw += v3.w;
            }
            for (; j < d; ++j) {
                float4 v = ((const float4*)(x + (long long)cp[j] * FD))[sub];
                ax += v.x; ay += v.y; az += v.z; aw += v.w;
            }
            float inv = 1.0f / fmaxf((float)d, 1.0f);
            float4 o; o.x = ax * inv; o.y = ay * inv; o.z = az * inv; o.w = aw * inv;
            *(float4*)&mslab[rlocal * 132 + sub * 4] = o;
            __syncthreads();
            if (wave == rg) {
#pragma unroll
                for (int kt = 0; kt < 4; ++kt)
#pragma unroll
                    for (int q = 0; q < 8; ++q)
                        macc[kt * 8 + q] = mslab[l15 * 132 + quad * 8 + kt * 32 + q];
            }
            __syncthreads();
        }
    }

    // ---- phase 2a: kt 0..3, A from macc registers (fully unrolled) ----
#pragma unroll
    for (int kt = 0; kt < 4; ++kt) {
        uint4 gh = ((const uint4*)(wt_hi + kt * 4096))[tid];
        uint4 gl = ((const uint4*)(wt_lo + kt * 4096))[tid];
        *(uint4*)&Bh[tid * 8] = gh;
        *(uint4*)&Bl[tid * 8] = gl;
        v8s a_h, a_l;
#pragma unroll
        for (int q = 0; q < 8; q++) {
            float fv = macc[kt * 8 + q];
            unsigned short hb = f2bf(fv);
            a_h[q] = (short)hb;
            a_l[q] = (short)f2bf(fv - bf2f(hb));
        }
        __syncthreads();
#pragma unroll
        for (int t = 0; t < 8; t++) {
            v8s b_h = *(const v8s*)&Bh[t * 512 + lane * 8];
            v8s b_l = *(const v8s*)&Bl[t * 512 + lane * 8];
            acc[t] = __builtin_amdgcn_mfma_f32_16x16x32_bf16(a_l, b_h, acc[t], 0, 0, 0);
            acc[t] = __builtin_amdgcn_mfma_f32_16x16x32_bf16(a_h, b_l, acc[t], 0, 0, 0);
            acc[t] = __builtin_amdgcn_mfma_f32_16x16x32_bf16(a_h, b_h, acc[t], 0, 0, 0);
        }
        __syncthreads();
    }
    // ---- phase 2b: kt 4..7, A direct from global x ----
    for (int kt = 4; kt < 8; ++kt) {
        uint4 gh = ((const uint4*)(wt_hi + kt * 4096))[tid];
        uint4 gl = ((const uint4*)(wt_lo + kt * 4096))[tid];
        const float* ap = x + (long long)growA * FD + (kt - 4) * 32 + quad * 8;
        float4 v0 = *(const float4*)(ap);
        float4 v1 = *(const float4*)(ap + 4);
        *(uint4*)&Bh[tid * 8] = gh;
        *(uint4*)&Bl[tid * 8] = gl;
        float f[8] = {v0.x, v0.y, v0.z, v0.w, v1.x, v1.y, v1.z, v1.w};
        v8s a_h, a_l;
#pragma unroll
        for (int q = 0; q < 8; q++) {
            unsigned short hb = f2bf(f[q]);
            a_h[q] = (short)hb;
            a_l[q] = (short)f2bf(f[q] - bf2f(hb));
        }
        __syncthreads();
#pragma unroll
        for (int t = 0; t < 8; t++) {
            v8s b_h = *(const v8s*)&Bh[t * 512 + lane * 8];
            v8s b_l = *(const v8s*)&Bl[t * 512 + lane * 8];
            acc[t] = __builtin_amdgcn_mfma_f32_16x16x32_bf16(a_l, b_h, acc[t], 0, 0, 0);
            acc[t] = __builtin_amdgcn_mfma_f32_16x16x32_bf16(a_h, b_l, acc[t], 0, 0, 0);
            acc[t] = __builtin_amdgcn_mfma_f32_16x16x32_bf16(a_h, b_h, acc[t], 0, 0, 0);
        }
        __syncthreads();
    }

    // ---- epilogue: bias + relu + store h + score partials ----
    int rbase = row0 + 16 * wave + quad * 4;
    float part[4] = {0.f, 0.f, 0.f, 0.f};
#pragma unroll
    for (int t = 0; t < 8; t++) {
        int colc = t * 16 + l15;
        float blv = bl[colc];
        float pwv = pw[colc];
#pragma unroll
        for (int reg = 0; reg < 4; reg++) {
            float h = fmaxf(acc[t][reg] + blv, 0.0f);
            part[reg] += h * pwv;
            int grow = rbase + reg;
            if (grow < M) hout[(long long)grow * FD + colc] = h;
        }
    }
#pragma unroll
    for (int reg = 0; reg < 4; reg++)
        spart[(16 * wave + quad * 4 + reg) * 16 + l15] = part[reg];
    __syncthreads();
    if (tid < 128) {
        int grow = row0 + tid;
        if (grow < M) {
            float dot = 0.0f;
#pragma unroll
            for (int i = 0; i < 16; i++) dot += spart[tid * 16 + i];
            float nr = 0.0f;
#pragma unroll
            for (int i = 0; i < 16; i++) nr += snrmp[i];
            score[grow] = tanhf(dot / sqrtf(nr));
        }
    }
}

// ---------------- per-graph tail, phase-split across 2 blocks/graph ----------------
//   kind 0: edge remap + next-layer CSR + deg (+ gmap init at layer 1)
//   kind 1: pool -> xp, readout -> z (+ final MLP in mode 2)
__global__ __launch_bounds__(1024) void topk_tail_kernel(
        const float* __restrict__ score, const float* __restrict__ hout,
        int n_per, int k, int SN,
        float* __restrict__ xp,
        const int* __restrict__ esrc, const int* __restrict__ edst,
        int* __restrict__ gmap,
        int* __restrict__ next_deg, int* __restrict__ next_col,
        float* __restrict__ z, int mode,
        const float* __restrict__ W1, const float* __restrict__ b1,
        const float* __restrict__ W2, const float* __restrict__ b2,
        const float* __restrict__ W3, const float* __restrict__ b3,
        float* __restrict__ out) {
    __shared__ float skey[512];
    __shared__ int   sidx[512];
    __shared__ unsigned long long spk[512];
    __shared__ int   lmap[512];
    __shared__ int   lcnt[512];
    __shared__ float pmax[1024];
    __shared__ float psum[1024];
    __shared__ float zs[256], t1[128], t2[64], t3[16];
    int tid = threadIdx.x;
    int kind, b;
    if (mode == 2) { kind = 1; b = swz(blockIdx.x, BG); }
    else {
        kind = blockIdx.x >= BG ? 1 : 0;
        b = swz(kind ? blockIdx.x - BG : blockIdx.x, BG);
    }

    if (kind == 0)
        for (int i = tid; i < SN; i += 1024) { lmap[i] = -1; lcnt[i] = 0; }

    // ---- register bitonic sort on packed keys (desc key, asc idx) ----
    unsigned long long P = 0ULL;
    if (tid < SN) {
        float keyv; unsigned int idx;
        if (tid < n_per) { keyv = score[b * n_per + tid]; idx = (unsigned int)tid; }
        else             { keyv = -INFINITY;              idx = 0x7fffffffu; }
        unsigned int u = __float_as_uint(keyv);
        u = (u & 0x80000000u) ? ~u : (u | 0x80000000u);
        P = ((unsigned long long)u << 32) | (unsigned long long)(~idx);
    }
    for (int ks = 2; ks <= SN; ks <<= 1) {
        for (int j = ks >> 1; j > 0; j >>= 1) {
            unsigned long long Q;
            if (j >= 64) {
                __syncthreads();
                if (tid < SN) spk[tid] = P;
                __syncthreads();
                Q = (tid < SN) ? spk[tid ^ j] : 0ULL;
            } else {
                Q = __shfl_xor(P, j, 64);
            }
            if (tid < SN) {
                bool keepmax = (((tid & ks) == 0) == ((tid & j) == 0));
                if (keepmax == (Q > P)) P = Q;
            }
        }
    }
    if (tid < SN) {
        unsigned int u  = (unsigned int)(P >> 32);
        unsigned int fb = (u & 0x80000000u) ? (u & 0x7fffffffu) : ~u;
        int iv = (int)(~(unsigned int)P);
        skey[tid] = __uint_as_float(fb);
        sidx[tid] = iv;
        if (kind == 0 && tid < k) lmap[iv] = tid;
    }
    __syncthreads();

    if (kind == 0) {
        // ---- edge remap + CSR build for next layer ----
        int kbase = b * k;
        if (mode == 0) {
            int nbase = b * n_per;      // n_per == NPG, original ids
            for (int e0 = tid; e0 < EPG; e0 += 1024) {
                int e = b * EPG + e0;
                int ls = lmap[esrc[e] - nbase];
                int ld = lmap[edst[e] - nbase];
                if (ls >= 0 && ld >= 0) {
                    int pos = atomicAdd(&lcnt[ld], 1);
                    if (pos < CAP) next_col[(long long)(kbase + ld) * CAP + pos] = kbase + ls;
                }
            }
            __syncthreads();
            // gmap: original node -> level-1 global id (or -1)
            for (int i = tid; i < NPG; i += 1024) {
                int l = lmap[i];
                gmap[nbase + i] = l >= 0 ? kbase + l : -1;
            }
        } else {
            // mode 1: original edges composed through gmap (level-1 ids), then lmap
            int kb1 = b * n_per;        // n_per == K1, level-1 global base
            for (int e0 = tid; e0 < EPG; e0 += 1024) {
                int e = b * EPG + e0;
                int ws = gmap[esrc[e]];
                int wd = gmap[edst[e]];
                int ls = (ws >= 0) ? lmap[ws - kb1] : -1;
                int ld = (wd >= 0) ? lmap[wd - kb1] : -1;
                if (ls >= 0 && ld >= 0) {
                    int pos = atomicAdd(&lcnt[ld], 1);
                    if (pos < CAP) next_col[(long long)(kbase + ld) * CAP + pos] = kbase + ls;
                }
            }
            __syncthreads();
        }
        for (int i = tid; i < k; i += 1024) next_deg[kbase + i] = lcnt[i];
        return;
    }

    // ---- kind 1: pool -> xp, readout ----
    int c = tid & 127, s = tid >> 7;
    float mx = -INFINITY, sm = 0.0f;
    {
        int r = s;
        long long hbase = (long long)b * n_per * FD + c;
        long long xbase = (long long)b * k * FD + c;
        for (; r + 24 < k; r += 32) {
            int i0 = sidx[r], i1 = sidx[r + 8], i2 = sidx[r + 16], i3 = sidx[r + 24];
            float k0 = skey[r], k1 = skey[r + 8], k2 = skey[r + 16], k3 = skey[r + 24];
            float v0 = hout[hbase + (long long)i0 * FD] * k0;
            float v1 = hout[hbase + (long long)i1 * FD] * k1;
            float v2 = hout[hbase + (long long)i2 * FD] * k2;
            float v3 = hout[hbase + (long long)i3 * FD] * k3;
            if (mode != 2) {
                xp[xbase + (long long)(r)      * FD] = v0;
                xp[xbase + (long long)(r + 8)  * FD] = v1;
                xp[xbase + (long long)(r + 16) * FD] = v2;
                xp[xbase + (long long)(r + 24) * FD] = v3;
            }
            mx = fmaxf(mx, v0); sm += v0;
            mx = fmaxf(mx, v1); sm += v1;
            mx = fmaxf(mx, v2); sm += v2;
            mx = fmaxf(mx, v3); sm += v3;
        }
        for (; r < k; r += 8) {
            float v = hout[hbase + (long long)sidx[r] * FD] * skey[r];
            if (mode != 2) xp[xbase + (long long)r * FD] = v;
            mx = fmaxf(mx, v); sm += v;
        }
    }
    pmax[tid] = mx; psum[tid] = sm;
    __syncthreads();
    if (tid < 128) {
        float m = -INFINITY, su = 0.0f;
#pragma unroll
        for (int i = 0; i < 8; i++) {
            m = fmaxf(m, pmax[i * 128 + tid]);
            su += psum[i * 128 + tid];
        }
        float mean = su / (float)k;
        if (mode == 0)      { z[b * 256 + tid] = m;  z[b * 256 + 128 + tid] = mean;  }
        else if (mode == 1) { z[b * 256 + tid] += m; z[b * 256 + 128 + tid] += mean; }
        else {
            zs[tid]       = z[b * 256 + tid] + m;
            zs[128 + tid] = z[b * 256 + 128 + tid] + mean;
        }
    }
    if (mode == 2) {
        __syncthreads();
        if (tid < 128) {
            float a = b1[tid];
            for (int kk = 0; kk < 256; kk++) a += zs[kk] * W1[kk * 128 + tid];
            t1[tid] = fmaxf(a, 0.0f);
        }
        __syncthreads();
        if (tid < 64) {
            float a = b2[tid];
            for (int kk = 0; kk < 128; kk++) a += t1[kk] * W2[kk * 64 + tid];
            t2[tid] = fmaxf(a, 0.0f);
        }
        __syncthreads();
        if (tid < 10) {
            float a = b3[tid];
            for (int kk = 0; kk < 64; kk++) a += t2[kk] * W3[kk * 10 + tid];
            t3[tid] = a;
        }
        __syncthreads();
        if (tid == 0) {
            float m = -INFINITY;
            for (int i = 0; i < 10; i++) m = fmaxf(m, t3[i]);
            float su = 0.0f;
            for (int i = 0; i < 10; i++) su += expf(t3[i] - m);
            float ls = logf(su);
            for (int i = 0; i < 10; i++) out[b * 10 + i] = t3[i] - m - ls;
        }
    }
}

extern "C" void kernel_launch(void* const* d_in, const int* in_sizes, int n_in,
                              void* d_out, int out_size, void* d_ws, size_t ws_size,
                              hipStream_t stream) {
    (void)in_sizes; (void)n_in; (void)out_size; (void)ws_size;
    const float* x   = (const float*)d_in[0];
    const int*   ei  = (const int*)d_in[1];
    const float* Wl1 = (const float*)d_in[2];
    const float* bl1 = (const float*)d_in[3];
    const float* Wr1 = (const float*)d_in[4];
    const float* Wl2 = (const float*)d_in[5];
    const float* bl2 = (const float*)d_in[6];
    const float* Wr2 = (const float*)d_in[7];
    const float* Wl3 = (const float*)d_in[8];
    const float* bl3 = (const float*)d_in[9];
    const float* Wr3 = (const float*)d_in[10];
    const float* pw1 = (const float*)d_in[11];
    const float* pw2 = (const float*)d_in[12];
    const float* pw3 = (const float*)d_in[13];
    const float* W1  = (const float*)d_in[14];
    const float* b1  = (const float*)d_in[15];
    const float* W2  = (const float*)d_in[16];
    const float* b2  = (const float*)d_in[17];
    const float* W3  = (const float*)d_in[18];
    const float* b3  = (const float*)d_in[19];
    float* out = (float*)d_out;

    // workspace layout
    char* ws = (char*)d_ws;
    size_t off = 0;
    auto alloc = [&](size_t bytes) {
        char* p = ws + off;
        off = (off + bytes + 255) & ~(size_t)255;
        return p;
    };
    float* hout  = (float*)alloc((size_t)NN * FD * 4);
    float* xp    = (float*)alloc((size_t)BG * K1 * FD * 4);
    float* sc    = (float*)alloc((size_t)NN * 4);
    int*   gmap  = (int*)  alloc((size_t)NN * 4);
    int*   deg   = (int*)  alloc((size_t)NN * 4);
    int*   colb  = (int*)  alloc((size_t)NN * CAP * 4);   // 12.8 MB
    float* z     = (float*)alloc((size_t)BG * 256 * 4);
    unsigned short* wt_hi = (unsigned short*)alloc((size_t)3 * 32768 * 2);
    unsigned short* wt_lo = (unsigned short*)alloc((size_t)3 * 32768 * 2);

    // ================= prep (CSR build + W conversion, one launch) =================
    prep_fill_kernel<<<BG + 96, 1024, 0, stream>>>(ei, deg, colb,
                                                   Wl1, Wr1, Wl2, Wr2, Wl3, Wr3, wt_hi, wt_lo);

    // ================= layer 1 =================
    {
        int nb = (NN + 127) / 128;
        sage_gemm_fused_kernel<<<nb, 512, 0, stream>>>(deg, colb, x, wt_hi, wt_lo,
                                                       bl1, pw1, hout, sc, NN, nb);
    }
    topk_tail_kernel<<<2 * BG, 1024, 0, stream>>>(sc, hout, NPG, K1, 512, xp,
                                                  ei, ei + EE, gmap, deg, colb,
                                                  z, 0, W1, b1, W2, b2, W3, b3, out);

    // ================= layer 2 =================
    const int N2 = BG * K1;   // 25000
    {
        int nb = (N2 + 127) / 128;
        sage_gemm_fused_kernel<<<nb, 512, 0, stream>>>(deg, colb, xp, wt_hi + 32768, wt_lo + 32768,
                                                       bl2, pw2, hout, sc, N2, nb);
    }
    topk_tail_kernel<<<2 * BG, 1024, 0, stream>>>(sc, hout, K1, K2, 256, xp,
                                                  ei, ei + EE, gmap, deg, colb,
                                                  z, 1, W1, b1, W2, b2, W3, b3, out);

    // ================= layer 3 =================
    const int N3 = BG * K2;   // 12500
    {
        int nb = (N3 + 127) / 128;
        sage_gemm_fused_kernel<<<nb, 512, 0, stream>>>(deg, colb, xp, wt_hi + 65536, wt_lo + 65536,
                                                       bl3, pw3, hout, sc, N3, nb);
    }
    topk_tail_kernel<<<BG, 1024, 0, stream>>>(sc, hout, K2, K3, 128, (float*)0,
                                              (const int*)0, (const int*)0, (int*)0,
                                              (int*)0, (int*)0,
                                              z, 2, W1, b1, W2, b2, W3, b3, out);
}

// Round 8
// 253.292 us; speedup vs baseline: 1.0690x; 1.0690x over previous
//
#include <hip/hip_runtime.h>
#include <math.h>

// Problem constants (from reference)
#define BG    100        // graphs
#define NPG   500        // nodes per graph (layer 1)
#define FD    128        // feature dim (F_IN == H == 128)
#define EE    600000     // edges
#define EPG   6000       // edges per graph (contiguous, never cross graphs)
#define NN    50000      // total nodes layer 1
#define K1    250
#define K2    125
#define K3    63
#define CAP   64         // max in-degree capacity

typedef short v8s __attribute__((ext_vector_type(8)));
typedef float v4f __attribute__((ext_vector_type(4)));

// XCD-aligned swizzle (R9 win)
__device__ __forceinline__ int swz(int p, int N) {
    int j = p & 7, i = p >> 3;
    int chunk = N >> 3, rem = N & 7;
    int mj = j < rem ? j : rem;
    return j * chunk + mj + i;
}

// float -> bf16 RNE bits
__device__ __forceinline__ unsigned short f2bf(float f) {
    unsigned int u = __float_as_uint(f);
    unsigned int r = (u + 0x7FFFu + ((u >> 16) & 1u)) >> 16;
    return (unsigned short)r;
}
__device__ __forceinline__ float bf2f(unsigned short b) {
    return __uint_as_float(((unsigned int)b) << 16);
}

// ---------------- merged prep: blocks [0,BG) build layer-1 CSR (LDS counters);
// blocks [BG, BG+96) convert W -> Wt_hi/Wt_lo bf16 in MFMA-staging order:
// o = [layer][kt=k>>5][t=n>>4][quad=(k>>3)&3][l15=n&15][q=k&7]  (k = [Wl | Wr] rows)
__global__ __launch_bounds__(1024) void prep_fill_kernel(
        const int* __restrict__ ei, int* __restrict__ deg, int* __restrict__ col,
        const float* __restrict__ Wl1, const float* __restrict__ Wr1,
        const float* __restrict__ Wl2, const float* __restrict__ Wr2,
        const float* __restrict__ Wl3, const float* __restrict__ Wr3,
        unsigned short* __restrict__ wt_hi, unsigned short* __restrict__ wt_lo) {
    __shared__ int lcnt[NPG];
    int tid = threadIdx.x;
    if (blockIdx.x < BG) {
        int b = swz(blockIdx.x, BG);
        for (int i = tid; i < NPG; i += 1024) lcnt[i] = 0;
        __syncthreads();
        for (int e0 = tid; e0 < EPG; e0 += 1024) {
            int e = b * EPG + e0;
            int d = ei[EE + e];
            int pos = atomicAdd(&lcnt[d - b * NPG], 1);
            if (pos < CAP) col[(long long)d * CAP + pos] = ei[e];
        }
        __syncthreads();
        for (int i = tid; i < NPG; i += 1024) deg[b * NPG + i] = lcnt[i];
    } else {
        int id = (blockIdx.x - BG) * 1024 + tid;          // 3*256*128 = 98304
        if (id >= 3 * 256 * 128) return;
        int layer = id >> 15, rem = id & 32767;
        int k = rem >> 7, n = rem & 127;
        const float* Wl = layer == 0 ? Wl1 : (layer == 1 ? Wl2 : Wl3);
        const float* Wr = layer == 0 ? Wr1 : (layer == 1 ? Wr2 : Wr3);
        float w = (k < 128) ? Wl[k * 128 + n] : Wr[(k - 128) * 128 + n];
        unsigned short hi = f2bf(w);
        unsigned short lo = f2bf(w - bf2f(hi));
        long long o = (long long)layer * 32768
                    + (long long)(k >> 5) * 4096          // kt
                    + (long long)(n >> 4) * 512           // t
                    + (long long)((k >> 3) & 3) * 128     // quad
                    + (long long)(n & 15) * 8             // l15
                    + (k & 7);                            // q
        wt_hi[o] = hi;
        wt_lo[o] = lo;
    }
}

// ---------------- gather-aggregate layer 1 (coalesced, high TLP, 8-way pipelined) ----
__global__ void gather_agg_kernel(const int* __restrict__ deg, const int* __restrict__ col,
                                  const float* __restrict__ x, float* __restrict__ mean,
                                  int n, int NB) {
    int g = swz(blockIdx.x, NB) * 256 + threadIdx.x;
    int node = g >> 5, sub = g & 31;
    if (node >= n) return;
    int d = deg[node]; if (d > CAP) d = CAP;
    const int* cp = col + (long long)node * CAP;
    float ax = 0.0f, ay = 0.0f, az = 0.0f, aw = 0.0f;
    int j = 0;
    for (; j + 8 <= d; j += 8) {
        float4 v0 = ((const float4*)(x + (long long)cp[j]     * FD))[sub];
        float4 v1 = ((const float4*)(x + (long long)cp[j + 1] * FD))[sub];
        float4 v2 = ((const float4*)(x + (long long)cp[j + 2] * FD))[sub];
        float4 v3 = ((const float4*)(x + (long long)cp[j + 3] * FD))[sub];
        float4 v4 = ((const float4*)(x + (long long)cp[j + 4] * FD))[sub];
        float4 v5 = ((const float4*)(x + (long long)cp[j + 5] * FD))[sub];
        float4 v6 = ((const float4*)(x + (long long)cp[j + 6] * FD))[sub];
        float4 v7 = ((const float4*)(x + (long long)cp[j + 7] * FD))[sub];
        ax += v0.x; ay += v0.y; az += v0.z; aw += v0.w;
        ax += v1.x; ay += v1.y; az += v1.z; aw += v1.w;
        ax += v2.x; ay += v2.y; az += v2.z; aw += v2.w;
        ax += v3.x; ay += v3.y; az += v3.z; aw += v3.w;
        ax += v4.x; ay += v4.y; az += v4.z; aw += v4.w;
        ax += v5.x; ay += v5.y; az += v5.z; aw += v5.w;
        ax += v6.x; ay += v6.y; az += v6.z; aw += v6.w;
        ax += v7.x; ay += v7.y; az += v7.z; aw += v7.w;
    }
    for (; j + 4 <= d; j += 4) {
        float4 v0 = ((const float4*)(x + (long long)cp[j]     * FD))[sub];
        float4 v1 = ((const float4*)(x + (long long)cp[j + 1] * FD))[sub];
        float4 v2 = ((const float4*)(x + (long long)cp[j + 2] * FD))[sub];
        float4 v3 = ((const float4*)(x + (long long)cp[j + 3] * FD))[sub];
        ax += v0.x; ay += v0.y; az += v0.z; aw += v0.w;
        ax += v1.x; ay += v1.y; az += v1.z; aw += v1.w;
        ax += v2.x; ay += v2.y; az += v2.z; aw += v2.w;
        ax += v3.x; ay += v3.y; az += v3.z; aw += v3.w;
    }
    for (; j < d; ++j) {
        float4 v = ((const float4*)(x + (long long)cp[j] * FD))[sub];
        ax += v.x; ay += v.y; az += v.z; aw += v.w;
    }
    float inv = 1.0f / fmaxf((float)d, 1.0f);
    float4 o; o.x = ax * inv; o.y = ay * inv; o.z = az * inv; o.w = aw * inv;
    ((float4*)(mean + (long long)node * FD))[sub] = o;
}

// ---------------- SAGE GEMM layer 1 (R6 form: 128-row tile, 8 waves) -------------
__global__ __launch_bounds__(512) void sage_gemm_mfma_kernel(
        const float* __restrict__ mean, const float* __restrict__ x,
        const unsigned short* __restrict__ wt_hi, const unsigned short* __restrict__ wt_lo,
        const float* __restrict__ bl, const float* __restrict__ pw,
        float* __restrict__ hout, float* __restrict__ score, int M, int NB) {
    __shared__ unsigned short Bh[4096], Bl[4096];   // one kt-slab: [t][quad][l15][q]
    __shared__ float spart[128 * 16];
    __shared__ float snrmp[16];
    int tid  = threadIdx.x;
    int wave = tid >> 6, lane = tid & 63;
    int quad = lane >> 4, l15 = lane & 15;
    int row0 = swz(blockIdx.x, NB) * 128;

    v4f acc[8];
#pragma unroll
    for (int t = 0; t < 8; t++) acc[t] = (v4f){0.f, 0.f, 0.f, 0.f};

    if (tid < 16) {
        float s = 0.f;
#pragma unroll
        for (int t = 0; t < 8; t++) { float p = pw[t * 16 + tid]; s += p * p; }
        snrmp[tid] = s;
    }

    int growA = row0 + 16 * wave + l15; if (growA > M - 1) growA = M - 1;

    for (int kt = 0; kt < 8; ++kt) {
        uint4 gh = ((const uint4*)(wt_hi + kt * 4096))[tid];
        uint4 gl = ((const uint4*)(wt_lo + kt * 4096))[tid];
        const float* Ab = (kt < 4) ? mean : x;
        const float* ap = Ab + (long long)growA * FD + ((kt < 4) ? kt : kt - 4) * 32 + quad * 8;
        float4 v0 = *(const float4*)(ap);
        float4 v1 = *(const float4*)(ap + 4);
        *(uint4*)&Bh[tid * 8] = gh;
        *(uint4*)&Bl[tid * 8] = gl;
        float f[8] = {v0.x, v0.y, v0.z, v0.w, v1.x, v1.y, v1.z, v1.w};
        v8s a_h, a_l;
#pragma unroll
        for (int q = 0; q < 8; q++) {
            unsigned short hb = f2bf(f[q]);
            a_h[q] = (short)hb;
            a_l[q] = (short)f2bf(f[q] - bf2f(hb));
        }
        __syncthreads();
#pragma unroll
        for (int t = 0; t < 8; t++) {
            v8s b_h = *(const v8s*)&Bh[t * 512 + lane * 8];
            v8s b_l = *(const v8s*)&Bl[t * 512 + lane * 8];
            acc[t] = __builtin_amdgcn_mfma_f32_16x16x32_bf16(a_l, b_h, acc[t], 0, 0, 0);
            acc[t] = __builtin_amdgcn_mfma_f32_16x16x32_bf16(a_h, b_l, acc[t], 0, 0, 0);
            acc[t] = __builtin_amdgcn_mfma_f32_16x16x32_bf16(a_h, b_h, acc[t], 0, 0, 0);
        }
        __syncthreads();
    }

    int rbase = row0 + 16 * wave + quad * 4;
    float part[4] = {0.f, 0.f, 0.f, 0.f};
#pragma unroll
    for (int t = 0; t < 8; t++) {
        int colc = t * 16 + l15;
        float blv = bl[colc];
        float pwv = pw[colc];
#pragma unroll
        for (int reg = 0; reg < 4; reg++) {
            float h = fmaxf(acc[t][reg] + blv, 0.0f);
            part[reg] += h * pwv;
            int grow = rbase + reg;
            if (grow < M) hout[(long long)grow * FD + colc] = h;
        }
    }
#pragma unroll
    for (int reg = 0; reg < 4; reg++)
        spart[(16 * wave + quad * 4 + reg) * 16 + l15] = part[reg];
    __syncthreads();
    if (tid < 128) {
        int grow = row0 + tid;
        if (grow < M) {
            float dot = 0.0f;
#pragma unroll
            for (int i = 0; i < 16; i++) dot += spart[tid * 16 + i];
            float nr = 0.0f;
#pragma unroll
            for (int i = 0; i < 16; i++) nr += snrmp[i];
            score[grow] = tanhf(dot / sqrtf(nr));
        }
    }
}

// ================= mega tail: one block per graph, tail1 -> out ==================
// All phases are graph-local (edges never cross graphs). Inner loops are verbatim
// copies of the proven R6 kernels -> identical FP order. Layers 2/3 use private
// buffers (no cross-graph aliasing); gmap/z/score live in LDS.

__device__ __forceinline__ void sort_phase(const float* scoreSrc, int n_per, int SN, int tid,
        unsigned long long* spk, float* skey, int* sidx, int* lmap, int kset) {
    unsigned long long P = 0ULL;
    if (tid < SN) {
        float keyv; unsigned int idx;
        if (tid < n_per) { keyv = scoreSrc[tid]; idx = (unsigned int)tid; }
        else             { keyv = -INFINITY;     idx = 0x7fffffffu; }
        unsigned int u = __float_as_uint(keyv);
        u = (u & 0x80000000u) ? ~u : (u | 0x80000000u);
        P = ((unsigned long long)u << 32) | (unsigned long long)(~idx);
    }
    for (int ks = 2; ks <= SN; ks <<= 1) {
        for (int j = ks >> 1; j > 0; j >>= 1) {
            unsigned long long Q;
            if (j >= 64) {
                __syncthreads();
                if (tid < SN) spk[tid] = P;
                __syncthreads();
                Q = (tid < SN) ? spk[tid ^ j] : 0ULL;
            } else {
                Q = __shfl_xor(P, j, 64);
            }
            if (tid < SN) {
                bool keepmax = (((tid & ks) == 0) == ((tid & j) == 0));
                if (keepmax == (Q > P)) P = Q;
            }
        }
    }
    if (tid < SN) {
        unsigned int u  = (unsigned int)(P >> 32);
        unsigned int fb = (u & 0x80000000u) ? (u & 0x7fffffffu) : ~u;
        int iv = (int)(~(unsigned int)P);
        skey[tid] = __uint_as_float(fb);
        sidx[tid] = iv;
        if (tid < kset) lmap[iv] = tid;
    }
}

__device__ __forceinline__ void pool_phase(const float* __restrict__ hb, float* __restrict__ xb,
        const float* skey, const int* sidx, float* pmax, float* psum,
        float* zsum, float* zs, int k, int tid, int mode) {
    int c = tid & 127, s = tid >> 7;
    float mx = -INFINITY, sm = 0.0f;
    int r = s;
    for (; r + 24 < k; r += 32) {
        int i0 = sidx[r], i1 = sidx[r + 8], i2 = sidx[r + 16], i3 = sidx[r + 24];
        float k0 = skey[r], k1 = skey[r + 8], k2 = skey[r + 16], k3 = skey[r + 24];
        float v0 = hb[c + (long long)i0 * FD] * k0;
        float v1 = hb[c + (long long)i1 * FD] * k1;
        float v2 = hb[c + (long long)i2 * FD] * k2;
        float v3 = hb[c + (long long)i3 * FD] * k3;
        if (xb) {
            xb[c + (long long)(r)      * FD] = v0;
            xb[c + (long long)(r + 8)  * FD] = v1;
            xb[c + (long long)(r + 16) * FD] = v2;
            xb[c + (long long)(r + 24) * FD] = v3;
        }
        mx = fmaxf(mx, v0); sm += v0;
        mx = fmaxf(mx, v1); sm += v1;
        mx = fmaxf(mx, v2); sm += v2;
        mx = fmaxf(mx, v3); sm += v3;
    }
    for (; r < k; r += 8) {
        float v = hb[c + (long long)sidx[r] * FD] * skey[r];
        if (xb) xb[c + (long long)r * FD] = v;
        mx = fmaxf(mx, v); sm += v;
    }
    pmax[tid] = mx; psum[tid] = sm;
    __syncthreads();
    if (tid < 128) {
        float m = -INFINITY, su = 0.0f;
#pragma unroll
        for (int i = 0; i < 8; i++) {
            m = fmaxf(m, pmax[i * 128 + tid]);
            su += psum[i * 128 + tid];
        }
        float mean = su / (float)k;
        if (mode == 0)      { zsum[tid] = m;  zsum[128 + tid] = mean;  }
        else if (mode == 1) { zsum[tid] += m; zsum[128 + tid] += mean; }
        else { zs[tid] = zsum[tid] + m; zs[128 + tid] = zsum[128 + tid] + mean; }
    }
}

__device__ __forceinline__ void gather_phase(const int* lcnt, const int* __restrict__ colX,
        const float* __restrict__ xsrc, float* __restrict__ meanX,
        int kbase, int k, int tid) {
    int sub = tid & 31;
    for (int base = 0; base < k; base += 32) {
        int nl = base + (tid >> 5);
        if (nl < k) {
            int d = lcnt[nl]; if (d > CAP) d = CAP;
            const int* cp = colX + (long long)(kbase + nl) * CAP;
            float ax = 0.0f, ay = 0.0f, az = 0.0f, aw = 0.0f;
            int j = 0;
            for (; j + 8 <= d; j += 8) {
                float4 v0 = ((const float4*)(xsrc + (long long)cp[j]     * FD))[sub];
                float4 v1 = ((const float4*)(xsrc + (long long)cp[j + 1] * FD))[sub];
                float4 v2 = ((const float4*)(xsrc + (long long)cp[j + 2] * FD))[sub];
                float4 v3 = ((const float4*)(xsrc + (long long)cp[j + 3] * FD))[sub];
                float4 v4 = ((const float4*)(xsrc + (long long)cp[j + 4] * FD))[sub];
                float4 v5 = ((const float4*)(xsrc + (long long)cp[j + 5] * FD))[sub];
                float4 v6 = ((const float4*)(xsrc + (long long)cp[j + 6] * FD))[sub];
                float4 v7 = ((const float4*)(xsrc + (long long)cp[j + 7] * FD))[sub];
                ax += v0.x; ay += v0.y; az += v0.z; aw += v0.w;
                ax += v1.x; ay += v1.y; az += v1.z; aw += v1.w;
                ax += v2.x; ay += v2.y; az += v2.z; aw += v2.w;
                ax += v3.x; ay += v3.y; az += v3.z; aw += v3.w;
                ax += v4.x; ay += v4.y; az += v4.z; aw += v4.w;
                ax += v5.x; ay += v5.y; az += v5.z; aw += v5.w;
                ax += v6.x; ay += v6.y; az += v6.z; aw += v6.w;
                ax += v7.x; ay += v7.y; az += v7.z; aw += v7.w;
            }
            for (; j + 4 <= d; j += 4) {
                float4 v0 = ((const float4*)(xsrc + (long long)cp[j]     * FD))[sub];
                float4 v1 = ((const float4*)(xsrc + (long long)cp[j + 1] * FD))[sub];
                float4 v2 = ((const float4*)(xsrc + (long long)cp[j + 2] * FD))[sub];
                float4 v3 = ((const float4*)(xsrc + (long long)cp[j + 3] * FD))[sub];
                ax += v0.x; ay += v0.y; az += v0.z; aw += v0.w;
                ax += v1.x; ay += v1.y; az += v1.z; aw += v1.w;
                ax += v2.x; ay += v2.y; az += v2.z; aw += v2.w;
                ax += v3.x; ay += v3.y; az += v3.z; aw += v3.w;
            }
            for (; j < d; ++j) {
                float4 v = ((const float4*)(xsrc + (long long)cp[j] * FD))[sub];
                ax += v.x; ay += v.y; az += v.z; aw += v.w;
            }
            float inv = 1.0f / fmaxf((float)d, 1.0f);
            float4 o; o.x = ax * inv; o.y = ay * inv; o.z = az * inv; o.w = aw * inv;
            ((float4*)(meanX + (long long)(kbase + nl) * FD))[sub] = o;
        }
    }
}

__device__ __forceinline__ void gemm_phase(const float* __restrict__ meanX,
        const float* __restrict__ xsrc,
        const unsigned short* __restrict__ wh, const unsigned short* __restrict__ wl,
        const float* __restrict__ blv, const float* __restrict__ pwv,
        float* __restrict__ hX, float* scoreL, float* snrmp,
        unsigned short* Bh, unsigned short* Bl, float* spart,
        int kbase, int krows, int tid, int wave, int lane, int quad, int l15) {
    v4f acc[8];
#pragma unroll
    for (int t = 0; t < 8; t++) acc[t] = (v4f){0.f, 0.f, 0.f, 0.f};
    if (tid < 16) {
        float s = 0.f;
#pragma unroll
        for (int t = 0; t < 8; t++) { float p = pwv[t * 16 + tid]; s += p * p; }
        snrmp[tid] = s;
    }
    int rowEnd = kbase + krows;
    int growA = kbase + 16 * wave + l15; if (growA > rowEnd - 1) growA = rowEnd - 1;
    for (int kt = 0; kt < 8; ++kt) {
        uint4 gh, gl;
        if (tid < 512) {
            gh = ((const uint4*)(wh + kt * 4096))[tid];
            gl = ((const uint4*)(wl + kt * 4096))[tid];
        }
        const float* Ab = (kt < 4) ? meanX : xsrc;
        const float* ap = Ab + (long long)growA * FD + ((kt < 4) ? kt : kt - 4) * 32 + quad * 8;
        float4 v0 = *(const float4*)(ap);
        float4 v1 = *(const float4*)(ap + 4);
        if (tid < 512) {
            *(uint4*)&Bh[tid * 8] = gh;
            *(uint4*)&Bl[tid * 8] = gl;
        }
        float f[8] = {v0.x, v0.y, v0.z, v0.w, v1.x, v1.y, v1.z, v1.w};
        v8s a_h, a_l;
#pragma unroll
        for (int q = 0; q < 8; q++) {
            unsigned short hb2 = f2bf(f[q]);
            a_h[q] = (short)hb2;
            a_l[q] = (short)f2bf(f[q] - bf2f(hb2));
        }
        __syncthreads();
#pragma unroll
        for (int t = 0; t < 8; t++) {
            v8s b_h = *(const v8s*)&Bh[t * 512 + lane * 8];
            v8s b_l = *(const v8s*)&Bl[t * 512 + lane * 8];
            acc[t] = __builtin_amdgcn_mfma_f32_16x16x32_bf16(a_l, b_h, acc[t], 0, 0, 0);
            acc[t] = __builtin_amdgcn_mfma_f32_16x16x32_bf16(a_h, b_l, acc[t], 0, 0, 0);
            acc[t] = __builtin_amdgcn_mfma_f32_16x16x32_bf16(a_h, b_h, acc[t], 0, 0, 0);
        }
        __syncthreads();
    }
    int rbase = kbase + 16 * wave + quad * 4;
    float part[4] = {0.f, 0.f, 0.f, 0.f};
#pragma unroll
    for (int t = 0; t < 8; t++) {
        int colc = t * 16 + l15;
        float blvv = blv[colc];
        float pwvv = pwv[colc];
#pragma unroll
        for (int reg = 0; reg < 4; reg++) {
            float h = fmaxf(acc[t][reg] + blvv, 0.0f);
            part[reg] += h * pwvv;
            int grow = rbase + reg;
            if (grow < rowEnd) hX[(long long)grow * FD + colc] = h;
        }
    }
#pragma unroll
    for (int reg = 0; reg < 4; reg++)
        spart[(16 * wave + quad * 4 + reg) * 16 + l15] = part[reg];
    __syncthreads();
    if (tid < krows) {
        float dot = 0.0f;
#pragma unroll
        for (int i = 0; i < 16; i++) dot += spart[tid * 16 + i];
        float nr = 0.0f;
#pragma unroll
        for (int i = 0; i < 16; i++) nr += snrmp[i];
        scoreL[tid] = tanhf(dot / sqrtf(nr));
    }
}

__global__ __launch_bounds__(1024) void mega_tail_kernel(
        const float* __restrict__ sc1, const float* __restrict__ h1,
        const int* __restrict__ ei,
        float* __restrict__ xp2, float* __restrict__ xp3,
        int* __restrict__ col2, int* __restrict__ col3,
        float* __restrict__ mean2, float* __restrict__ mean3,
        float* __restrict__ h2, float* __restrict__ h3,
        const unsigned short* __restrict__ wt_hi, const unsigned short* __restrict__ wt_lo,
        const float* __restrict__ bl2v, const float* __restrict__ pw2v,
        const float* __restrict__ bl3v, const float* __restrict__ pw3v,
        const float* __restrict__ W1, const float* __restrict__ b1,
        const float* __restrict__ W2, const float* __restrict__ b2,
        const float* __restrict__ W3, const float* __restrict__ b3,
        float* __restrict__ out) {
    __shared__ float skey[512];
    __shared__ int   sidx[512];
    __shared__ unsigned long long spk[512];
    __shared__ int   lmap[512];
    __shared__ int   lcnt[512];
    __shared__ int   gmapL[NPG];
    __shared__ float pmax[1024];
    __shared__ float psum[1024];
    __shared__ float zsum[256];
    __shared__ float zs[256], t1[128], t2[64], t3[16];
    __shared__ unsigned short Bh[4096], Bl[4096];
    __shared__ float spart[256 * 16];
    __shared__ float snrmp[16];
    __shared__ float scoreL[256];

    int tid = threadIdx.x;
    int b = swz(blockIdx.x, BG);
    int wave = tid >> 6, lane = tid & 63, quad = lane >> 4, l15 = lane & 15;
    const int* esrc = ei;
    const int* edst = ei + EE;
    int nbase = b * NPG;

    // ===================== tail1: sort + CSR(layer2) + pool + readout =====================
    for (int i = tid; i < 512; i += 1024) { lmap[i] = -1; lcnt[i] = 0; }
    __syncthreads();
    sort_phase(sc1 + (long long)b * NPG, NPG, 512, tid, spk, skey, sidx, lmap, K1);
    __syncthreads();
    {   // edge remap layer1 -> layer2 CSR + gmapL
        int kbase = b * K1;
        for (int e0 = tid; e0 < EPG; e0 += 1024) {
            int e = b * EPG + e0;
            int ls = lmap[esrc[e] - nbase];
            int ld = lmap[edst[e] - nbase];
            if (ls >= 0 && ld >= 0) {
                int pos = atomicAdd(&lcnt[ld], 1);
                if (pos < CAP) col2[(long long)(kbase + ld) * CAP + pos] = kbase + ls;
            }
        }
        __syncthreads();
        for (int i = tid; i < NPG; i += 1024) {
            int l = lmap[i];
            gmapL[i] = l >= 0 ? kbase + l : -1;
        }
    }
    __syncthreads();
    pool_phase(h1 + (long long)b * NPG * FD, xp2 + (long long)b * K1 * FD,
               skey, sidx, pmax, psum, zsum, zs, K1, tid, 0);
    __syncthreads();
    __threadfence_block();

    // ===================== gather2 + gemm2 =====================
    gather_phase(lcnt, col2, xp2, mean2, b * K1, K1, tid);
    __syncthreads();
    __threadfence_block();
    gemm_phase(mean2, xp2, wt_hi + 32768, wt_lo + 32768, bl2v, pw2v,
               h2, scoreL, snrmp, Bh, Bl, spart, b * K1, K1, tid, wave, lane, quad, l15);
    __syncthreads();
    __threadfence_block();

    // ===================== tail2: sort + CSR(layer3) + pool + readout =====================
    for (int i = tid; i < 256; i += 1024) { lmap[i] = -1; lcnt[i] = 0; }
    __syncthreads();
    sort_phase(scoreL, K1, 256, tid, spk, skey, sidx, lmap, K2);
    __syncthreads();
    {   // edge remap via gmapL composition -> layer3 CSR
        int kbase = b * K2, kb1 = b * K1;
        for (int e0 = tid; e0 < EPG; e0 += 1024) {
            int e = b * EPG + e0;
            int ws = gmapL[esrc[e] - nbase];
            int wd = gmapL[edst[e] - nbase];
            int ls = (ws >= 0) ? lmap[ws - kb1] : -1;
            int ld = (wd >= 0) ? lmap[wd - kb1] : -1;
            if (ls >= 0 && ld >= 0) {
                int pos = atomicAdd(&lcnt[ld], 1);
                if (pos < CAP) col3[(long long)(kbase + ld) * CAP + pos] = kbase + ls;
            }
        }
    }
    __syncthreads();
    pool_phase(h2 + (long long)b * K1 * FD, xp3 + (long long)b * K2 * FD,
               skey, sidx, pmax, psum, zsum, zs, K2, tid, 1);
    __syncthreads();
    __threadfence_block();

    // ===================== gather3 + gemm3 =====================
    gather_phase(lcnt, col3, xp3, mean3, b * K2, K2, tid);
    __syncthreads();
    __threadfence_block();
    gemm_phase(mean3, xp3, wt_hi + 65536, wt_lo + 65536, bl3v, pw3v,
               h3, scoreL, snrmp, Bh, Bl, spart, b * K2, K2, tid, wave, lane, quad, l15);
    __syncthreads();
    __threadfence_block();

    // ===================== tail3: sort + pool + MLP =====================
    sort_phase(scoreL, K2, 128, tid, spk, skey, sidx, lmap, 0);
    __syncthreads();
    pool_phase(h3 + (long long)b * K2 * FD, (float*)0,
               skey, sidx, pmax, psum, zsum, zs, K3, tid, 2);
    __syncthreads();
    if (tid < 128) {
        float a = b1[tid];
        for (int kk = 0; kk < 256; kk++) a += zs[kk] * W1[kk * 128 + tid];
        t1[tid] = fmaxf(a, 0.0f);
    }
    __syncthreads();
    if (tid < 64) {
        float a = b2[tid];
        for (int kk = 0; kk < 128; kk++) a += t1[kk] * W2[kk * 64 + tid];
        t2[tid] = fmaxf(a, 0.0f);
    }
    __syncthreads();
    if (tid < 10) {
        float a = b3[tid];
        for (int kk = 0; kk < 64; kk++) a += t2[kk] * W3[kk * 10 + tid];
        t3[tid] = a;
    }
    __syncthreads();
    if (tid == 0) {
        float m = -INFINITY;
        for (int i = 0; i < 10; i++) m = fmaxf(m, t3[i]);
        float su = 0.0f;
        for (int i = 0; i < 10; i++) su += expf(t3[i] - m);
        float ls = logf(su);
        for (int i = 0; i < 10; i++) out[b * 10 + i] = t3[i] - m - ls;
    }
}

extern "C" void kernel_launch(void* const* d_in, const int* in_sizes, int n_in,
                              void* d_out, int out_size, void* d_ws, size_t ws_size,
                              hipStream_t stream) {
    (void)in_sizes; (void)n_in; (void)out_size; (void)ws_size;
    const float* x   = (const float*)d_in[0];
    const int*   ei  = (const int*)d_in[1];
    const float* Wl1 = (const float*)d_in[2];
    const float* bl1 = (const float*)d_in[3];
    const float* Wr1 = (const float*)d_in[4];
    const float* Wl2 = (const float*)d_in[5];
    const float* bl2 = (const float*)d_in[6];
    const float* Wr2 = (const float*)d_in[7];
    const float* Wl3 = (const float*)d_in[8];
    const float* bl3 = (const float*)d_in[9];
    const float* Wr3 = (const float*)d_in[10];
    const float* pw1 = (const float*)d_in[11];
    const float* pw2 = (const float*)d_in[12];
    const float* pw3 = (const float*)d_in[13];
    const float* W1  = (const float*)d_in[14];
    const float* b1  = (const float*)d_in[15];
    const float* W2  = (const float*)d_in[16];
    const float* b2  = (const float*)d_in[17];
    const float* W3  = (const float*)d_in[18];
    const float* b3  = (const float*)d_in[19];
    float* out = (float*)d_out;

    // workspace layout
    char* ws = (char*)d_ws;
    size_t off = 0;
    auto alloc = [&](size_t bytes) {
        char* p = ws + off;
        off = (off + bytes + 255) & ~(size_t)255;
        return p;
    };
    const int N2 = BG * K1;   // 25000
    const int N3 = BG * K2;   // 12500
    float* mean1 = (float*)alloc((size_t)NN * FD * 4);
    float* h1    = (float*)alloc((size_t)NN * FD * 4);
    float* sc1   = (float*)alloc((size_t)NN * 4);
    int*   deg   = (int*)  alloc((size_t)NN * 4);
    int*   colb  = (int*)  alloc((size_t)NN * CAP * 4);   // layer-1 CSR
    float* xp2   = (float*)alloc((size_t)N2 * FD * 4);
    float* xp3   = (float*)alloc((size_t)N3 * FD * 4);
    int*   col2  = (int*)  alloc((size_t)N2 * CAP * 4);
    int*   col3  = (int*)  alloc((size_t)N3 * CAP * 4);
    float* mean2 = (float*)alloc((size_t)N2 * FD * 4);
    float* mean3 = (float*)alloc((size_t)N3 * FD * 4);
    float* h2    = (float*)alloc((size_t)N2 * FD * 4);
    float* h3    = (float*)alloc((size_t)N3 * FD * 4);
    unsigned short* wt_hi = (unsigned short*)alloc((size_t)3 * 32768 * 2);
    unsigned short* wt_lo = (unsigned short*)alloc((size_t)3 * 32768 * 2);

    // ================= prep (layer-1 CSR + W conversion) =================
    prep_fill_kernel<<<BG + 96, 1024, 0, stream>>>(ei, deg, colb,
                                                   Wl1, Wr1, Wl2, Wr2, Wl3, Wr3, wt_hi, wt_lo);

    // ================= layer 1 (device-wide TLP kernels) =================
    {
        int nb = (NN * 32 + 255) / 256;
        gather_agg_kernel<<<nb, 256, 0, stream>>>(deg, colb, x, mean1, NN, nb);
    }
    {
        int nb = (NN + 127) / 128;
        sage_gemm_mfma_kernel<<<nb, 512, 0, stream>>>(mean1, x, wt_hi, wt_lo,
                                                      bl1, pw1, h1, sc1, NN, nb);
    }

    // ================= everything else: one block per graph =================
    mega_tail_kernel<<<BG, 1024, 0, stream>>>(sc1, h1, ei,
                                              xp2, xp3, col2, col3, mean2, mean3, h2, h3,
                                              wt_hi, wt_lo, bl2, pw2, bl3, pw3,
                                              W1, b1, W2, b2, W3, b3, out);
}

// Round 9
// 237.809 us; speedup vs baseline: 1.1386x; 1.0651x over previous
//
#include <hip/hip_runtime.h>
#include <math.h>

// Problem constants (from reference)
#define BG    100        // graphs
#define NPG   500        // nodes per graph (layer 1)
#define FD    128        // feature dim (F_IN == H == 128)
#define EE    600000     // edges
#define EPG   6000       // edges per graph (contiguous, never cross graphs)
#define NN    50000      // total nodes layer 1
#define K1    250
#define K2    125
#define K3    63
#define CAP   64         // max in-degree capacity

typedef short v8s __attribute__((ext_vector_type(8)));
typedef float v4f __attribute__((ext_vector_type(4)));

// XCD-aligned swizzle (R9 win)
__device__ __forceinline__ int swz(int p, int N) {
    int j = p & 7, i = p >> 3;
    int chunk = N >> 3, rem = N & 7;
    int mj = j < rem ? j : rem;
    return j * chunk + mj + i;
}

// float -> bf16 RNE bits
__device__ __forceinline__ unsigned short f2bf(float f) {
    unsigned int u = __float_as_uint(f);
    unsigned int r = (u + 0x7FFFu + ((u >> 16) & 1u)) >> 16;
    return (unsigned short)r;
}
__device__ __forceinline__ float bf2f(unsigned short b) {
    return __uint_as_float(((unsigned int)b) << 16);
}

// ---------------- merged prep: blocks [0,BG) build layer-1 CSR (LDS counters);
// blocks [BG, BG+96) convert W -> Wt_hi/Wt_lo bf16 in MFMA-staging order:
// o = [layer][kt=k>>5][t=n>>4][quad=(k>>3)&3][l15=n&15][q=k&7]  (k = [Wl | Wr] rows)
__global__ __launch_bounds__(1024) void prep_fill_kernel(
        const int* __restrict__ ei, int* __restrict__ deg, int* __restrict__ col,
        const float* __restrict__ Wl1, const float* __restrict__ Wr1,
        const float* __restrict__ Wl2, const float* __restrict__ Wr2,
        const float* __restrict__ Wl3, const float* __restrict__ Wr3,
        unsigned short* __restrict__ wt_hi, unsigned short* __restrict__ wt_lo) {
    __shared__ int lcnt[NPG];
    int tid = threadIdx.x;
    if (blockIdx.x < BG) {
        int b = swz(blockIdx.x, BG);
        for (int i = tid; i < NPG; i += 1024) lcnt[i] = 0;
        __syncthreads();
        for (int e0 = tid; e0 < EPG; e0 += 1024) {
            int e = b * EPG + e0;
            int d = ei[EE + e];
            int pos = atomicAdd(&lcnt[d - b * NPG], 1);
            if (pos < CAP) col[(long long)d * CAP + pos] = ei[e];
        }
        __syncthreads();
        for (int i = tid; i < NPG; i += 1024) deg[b * NPG + i] = lcnt[i];
    } else {
        int id = (blockIdx.x - BG) * 1024 + tid;          // 3*256*128 = 98304
        if (id >= 3 * 256 * 128) return;
        int layer = id >> 15, rem = id & 32767;
        int k = rem >> 7, n = rem & 127;
        const float* Wl = layer == 0 ? Wl1 : (layer == 1 ? Wl2 : Wl3);
        const float* Wr = layer == 0 ? Wr1 : (layer == 1 ? Wr2 : Wr3);
        float w = (k < 128) ? Wl[k * 128 + n] : Wr[(k - 128) * 128 + n];
        unsigned short hi = f2bf(w);
        unsigned short lo = f2bf(w - bf2f(hi));
        long long o = (long long)layer * 32768
                    + (long long)(k >> 5) * 4096          // kt
                    + (long long)(n >> 4) * 512           // t
                    + (long long)((k >> 3) & 3) * 128     // quad
                    + (long long)(n & 15) * 8             // l15
                    + (k & 7);                            // q
        wt_hi[o] = hi;
        wt_lo[o] = lo;
    }
}

// ---------------- gather-aggregate (coalesced, high TLP, 8-way pipelined) ----------------
__global__ void gather_agg_kernel(const int* __restrict__ deg, const int* __restrict__ col,
                                  const float* __restrict__ x, float* __restrict__ mean,
                                  int n, int NB) {
    int g = swz(blockIdx.x, NB) * 256 + threadIdx.x;
    int node = g >> 5, sub = g & 31;
    if (node >= n) return;
    int d = deg[node]; if (d > CAP) d = CAP;
    const int* cp = col + (long long)node * CAP;
    float ax = 0.0f, ay = 0.0f, az = 0.0f, aw = 0.0f;
    int j = 0;
    for (; j + 8 <= d; j += 8) {
        float4 v0 = ((const float4*)(x + (long long)cp[j]     * FD))[sub];
        float4 v1 = ((const float4*)(x + (long long)cp[j + 1] * FD))[sub];
        float4 v2 = ((const float4*)(x + (long long)cp[j + 2] * FD))[sub];
        float4 v3 = ((const float4*)(x + (long long)cp[j + 3] * FD))[sub];
        float4 v4 = ((const float4*)(x + (long long)cp[j + 4] * FD))[sub];
        float4 v5 = ((const float4*)(x + (long long)cp[j + 5] * FD))[sub];
        float4 v6 = ((const float4*)(x + (long long)cp[j + 6] * FD))[sub];
        float4 v7 = ((const float4*)(x + (long long)cp[j + 7] * FD))[sub];
        ax += v0.x; ay += v0.y; az += v0.z; aw += v0.w;
        ax += v1.x; ay += v1.y; az += v1.z; aw += v1.w;
        ax += v2.x; ay += v2.y; az += v2.z; aw += v2.w;
        ax += v3.x; ay += v3.y; az += v3.z; aw += v3.w;
        ax += v4.x; ay += v4.y; az += v4.z; aw += v4.w;
        ax += v5.x; ay += v5.y; az += v5.z; aw += v5.w;
        ax += v6.x; ay += v6.y; az += v6.z; aw += v6.w;
        ax += v7.x; ay += v7.y; az += v7.z; aw += v7.w;
    }
    for (; j + 4 <= d; j += 4) {
        float4 v0 = ((const float4*)(x + (long long)cp[j]     * FD))[sub];
        float4 v1 = ((const float4*)(x + (long long)cp[j + 1] * FD))[sub];
        float4 v2 = ((const float4*)(x + (long long)cp[j + 2] * FD))[sub];
        float4 v3 = ((const float4*)(x + (long long)cp[j + 3] * FD))[sub];
        ax += v0.x; ay += v0.y; az += v0.z; aw += v0.w;
        ax += v1.x; ay += v1.y; az += v1.z; aw += v1.w;
        ax += v2.x; ay += v2.y; az += v2.z; aw += v2.w;
        ax += v3.x; ay += v3.y; az += v3.z; aw += v3.w;
    }
    for (; j < d; ++j) {
        float4 v = ((const float4*)(x + (long long)cp[j] * FD))[sub];
        ax += v.x; ay += v.y; az += v.z; aw += v.w;
    }
    float inv = 1.0f / fmaxf((float)d, 1.0f);
    float4 o; o.x = ax * inv; o.y = ay * inv; o.z = az * inv; o.w = aw * inv;
    ((float4*)(mean + (long long)node * FD))[sub] = o;
}

// ---------------- SAGE GEMM (128-row tile, 8 waves, double-buffered B staging) --------
// h = relu([mean|x]@[Wl;Wr] + bl), score = tanh(h.pw/||pw||).
// K-loop pipeline: stage kt into LDS[kt&1]; during MFMA of kt, prefetch kt+1 (B slab
// + A fragment) into registers; write them to LDS[(kt+1)&1] AFTER the barrier (no
// reader until the next barrier -> WAR-safe). ONE barrier per kt (was 2) and global
// load latency hides under MFMA+convert. Same values, same MFMA order -> bit-identical.
__global__ __launch_bounds__(512) void sage_gemm_mfma_kernel(
        const float* __restrict__ mean, const float* __restrict__ x,
        const unsigned short* __restrict__ wt_hi, const unsigned short* __restrict__ wt_lo,
        const float* __restrict__ bl, const float* __restrict__ pw,
        float* __restrict__ hout, float* __restrict__ score, int M, int NB) {
    __shared__ unsigned short Bh[2][4096], Bl[2][4096];   // kt-slab: [t][quad][l15][q]
    __shared__ float spart[128 * 16];
    __shared__ float snrmp[16];
    int tid  = threadIdx.x;
    int wave = tid >> 6, lane = tid & 63;
    int quad = lane >> 4, l15 = lane & 15;
    int row0 = swz(blockIdx.x, NB) * 128;

    v4f acc[8];
#pragma unroll
    for (int t = 0; t < 8; t++) acc[t] = (v4f){0.f, 0.f, 0.f, 0.f};

    if (tid < 16) {
        float s = 0.f;
#pragma unroll
        for (int t = 0; t < 8; t++) { float p = pw[t * 16 + tid]; s += p * p; }
        snrmp[tid] = s;
    }

    int growA = row0 + 16 * wave + l15; if (growA > M - 1) growA = M - 1;

    // ---- prologue: prefetch kt=0 and stage into LDS[0] ----
    uint4 gh = ((const uint4*)(wt_hi))[tid];
    uint4 gl = ((const uint4*)(wt_lo))[tid];
    const float* ap0 = mean + (long long)growA * FD + quad * 8;   // kt=0: mean, koff 0
    float4 av0 = *(const float4*)(ap0);
    float4 av1 = *(const float4*)(ap0 + 4);
    *(uint4*)&Bh[0][tid * 8] = gh;
    *(uint4*)&Bl[0][tid * 8] = gl;

    for (int kt = 0; kt < 8; ++kt) {
        int cur = kt & 1;
        // ---- convert current A to hi/lo in registers ----
        float f[8] = {av0.x, av0.y, av0.z, av0.w, av1.x, av1.y, av1.z, av1.w};
        v8s a_h, a_l;
#pragma unroll
        for (int q = 0; q < 8; q++) {
            unsigned short hb = f2bf(f[q]);
            a_h[q] = (short)hb;
            a_l[q] = (short)f2bf(f[q] - bf2f(hb));
        }
        // ---- issue prefetch for kt+1 (B slab + A fragment) ----
        if (kt < 7) {
            gh = ((const uint4*)(wt_hi + (kt + 1) * 4096))[tid];
            gl = ((const uint4*)(wt_lo + (kt + 1) * 4096))[tid];
            const float* Ab = (kt + 1 < 4) ? mean : x;
            const float* apn = Ab + (long long)growA * FD
                             + ((kt + 1 < 4) ? (kt + 1) : (kt - 3)) * 32 + quad * 8;
            av0 = *(const float4*)(apn);
            av1 = *(const float4*)(apn + 4);
        }
        __syncthreads();   // LDS[cur] fully staged by all threads
        // ---- MFMA over the 8 column tiles (conflict-free lane-contiguous reads) ----
#pragma unroll
        for (int t = 0; t < 8; t++) {
            v8s b_h = *(const v8s*)&Bh[cur][t * 512 + lane * 8];
            v8s b_l = *(const v8s*)&Bl[cur][t * 512 + lane * 8];
            acc[t] = __builtin_amdgcn_mfma_f32_16x16x32_bf16(a_l, b_h, acc[t], 0, 0, 0);
            acc[t] = __builtin_amdgcn_mfma_f32_16x16x32_bf16(a_h, b_l, acc[t], 0, 0, 0);
            acc[t] = __builtin_amdgcn_mfma_f32_16x16x32_bf16(a_h, b_h, acc[t], 0, 0, 0);
        }
        // ---- stage kt+1 into the other buffer (no reader until next barrier) ----
        if (kt < 7) {
            *(uint4*)&Bh[cur ^ 1][tid * 8] = gh;
            *(uint4*)&Bl[cur ^ 1][tid * 8] = gl;
        }
    }

    // ---- epilogue: bias + relu + store h + score partials ----
    int rbase = row0 + 16 * wave + quad * 4;
    float part[4] = {0.f, 0.f, 0.f, 0.f};
#pragma unroll
    for (int t = 0; t < 8; t++) {
        int colc = t * 16 + l15;
        float blv = bl[colc];
        float pwv = pw[colc];
#pragma unroll
        for (int reg = 0; reg < 4; reg++) {
            float h = fmaxf(acc[t][reg] + blv, 0.0f);
            part[reg] += h * pwv;
            int grow = rbase + reg;
            if (grow < M) hout[(long long)grow * FD + colc] = h;
        }
    }
#pragma unroll
    for (int reg = 0; reg < 4; reg++)
        spart[(16 * wave + quad * 4 + reg) * 16 + l15] = part[reg];
    __syncthreads();
    if (tid < 128) {
        int grow = row0 + tid;
        if (grow < M) {
            float dot = 0.0f;
#pragma unroll
            for (int i = 0; i < 16; i++) dot += spart[tid * 16 + i];
            float nr = 0.0f;
#pragma unroll
            for (int i = 0; i < 16; i++) nr += snrmp[i];
            score[grow] = tanhf(dot / sqrtf(nr));
        }
    }
}

// ---------------- per-graph tail, phase-split across 2 blocks/graph ----------------
// Both blocks of a graph run the (cheap, register-resident) bitonic sort; then:
//   kind 0: edge remap + next-layer CSR + deg (+ gmap init at layer 1)
//   kind 1: pool -> xp, readout -> z (+ final MLP in mode 2)
// Edge liveness across layers via composed node map gmap[original id] -> current
// level id or -1 (identical alive-set to the reference's emask composition).
__global__ __launch_bounds__(1024) void topk_tail_kernel(
        const float* __restrict__ score, const float* __restrict__ hout,
        int n_per, int k, int SN,
        float* __restrict__ xp,
        const int* __restrict__ esrc, const int* __restrict__ edst,
        int* __restrict__ gmap,
        int* __restrict__ next_deg, int* __restrict__ next_col,
        float* __restrict__ z, int mode,
        const float* __restrict__ W1, const float* __restrict__ b1,
        const float* __restrict__ W2, const float* __restrict__ b2,
        const float* __restrict__ W3, const float* __restrict__ b3,
        float* __restrict__ out) {
    __shared__ float skey[512];
    __shared__ int   sidx[512];
    __shared__ unsigned long long spk[512];
    __shared__ int   lmap[512];
    __shared__ int   lcnt[512];
    __shared__ float pmax[1024];
    __shared__ float psum[1024];
    __shared__ float zs[256], t1[128], t2[64], t3[16];
    int tid = threadIdx.x;
    int kind, b;
    if (mode == 2) { kind = 1; b = swz(blockIdx.x, BG); }
    else {
        kind = blockIdx.x >= BG ? 1 : 0;
        b = swz(kind ? blockIdx.x - BG : blockIdx.x, BG);
    }

    if (kind == 0)
        for (int i = tid; i < SN; i += 1024) { lmap[i] = -1; lcnt[i] = 0; }

    // ---- register bitonic sort on packed keys (desc key, asc idx) ----
    unsigned long long P = 0ULL;
    if (tid < SN) {
        float keyv; unsigned int idx;
        if (tid < n_per) { keyv = score[b * n_per + tid]; idx = (unsigned int)tid; }
        else             { keyv = -INFINITY;              idx = 0x7fffffffu; }
        unsigned int u = __float_as_uint(keyv);
        u = (u & 0x80000000u) ? ~u : (u | 0x80000000u);
        P = ((unsigned long long)u << 32) | (unsigned long long)(~idx);
    }
    for (int ks = 2; ks <= SN; ks <<= 1) {
        for (int j = ks >> 1; j > 0; j >>= 1) {
            unsigned long long Q;
            if (j >= 64) {
                __syncthreads();
                if (tid < SN) spk[tid] = P;
                __syncthreads();
                Q = (tid < SN) ? spk[tid ^ j] : 0ULL;
            } else {
                Q = __shfl_xor(P, j, 64);
            }
            if (tid < SN) {
                bool keepmax = (((tid & ks) == 0) == ((tid & j) == 0));
                if (keepmax == (Q > P)) P = Q;
            }
        }
    }
    if (tid < SN) {
        unsigned int u  = (unsigned int)(P >> 32);
        unsigned int fb = (u & 0x80000000u) ? (u & 0x7fffffffu) : ~u;
        int iv = (int)(~(unsigned int)P);
        skey[tid] = __uint_as_float(fb);
        sidx[tid] = iv;
        if (kind == 0 && tid < k) lmap[iv] = tid;
    }
    __syncthreads();

    if (kind == 0) {
        // ---- edge remap + CSR build for next layer ----
        int kbase = b * k;
        if (mode == 0) {
            int nbase = b * n_per;      // n_per == NPG, original ids
            for (int e0 = tid; e0 < EPG; e0 += 1024) {
                int e = b * EPG + e0;
                int ls = lmap[esrc[e] - nbase];
                int ld = lmap[edst[e] - nbase];
                if (ls >= 0 && ld >= 0) {
                    int pos = atomicAdd(&lcnt[ld], 1);
                    if (pos < CAP) next_col[(long long)(kbase + ld) * CAP + pos] = kbase + ls;
                }
            }
            __syncthreads();
            // gmap: original node -> level-1 global id (or -1)
            for (int i = tid; i < NPG; i += 1024) {
                int l = lmap[i];
                gmap[nbase + i] = l >= 0 ? kbase + l : -1;
            }
        } else {
            // mode 1: original edges composed through gmap (level-1 ids), then lmap
            int kb1 = b * n_per;        // n_per == K1, level-1 global base
            for (int e0 = tid; e0 < EPG; e0 += 1024) {
                int e = b * EPG + e0;
                int ws = gmap[esrc[e]];
                int wd = gmap[edst[e]];
                int ls = (ws >= 0) ? lmap[ws - kb1] : -1;
                int ld = (wd >= 0) ? lmap[wd - kb1] : -1;
                if (ls >= 0 && ld >= 0) {
                    int pos = atomicAdd(&lcnt[ld], 1);
                    if (pos < CAP) next_col[(long long)(kbase + ld) * CAP + pos] = kbase + ls;
                }
            }
            __syncthreads();
        }
        for (int i = tid; i < k; i += 1024) next_deg[kbase + i] = lcnt[i];
        return;
    }

    // ---- kind 1: pool -> xp, readout ----
    int c = tid & 127, s = tid >> 7;
    float mx = -INFINITY, sm = 0.0f;
    {
        int r = s;
        long long hbase = (long long)b * n_per * FD + c;
        long long xbase = (long long)b * k * FD + c;
        for (; r + 24 < k; r += 32) {
            int i0 = sidx[r], i1 = sidx[r + 8], i2 = sidx[r + 16], i3 = sidx[r + 24];
            float k0 = skey[r], k1 = skey[r + 8], k2 = skey[r + 16], k3 = skey[r + 24];
            float v0 = hout[hbase + (long long)i0 * FD] * k0;
            float v1 = hout[hbase + (long long)i1 * FD] * k1;
            float v2 = hout[hbase + (long long)i2 * FD] * k2;
            float v3 = hout[hbase + (long long)i3 * FD] * k3;
            if (mode != 2) {
                xp[xbase + (long long)(r)      * FD] = v0;
                xp[xbase + (long long)(r + 8)  * FD] = v1;
                xp[xbase + (long long)(r + 16) * FD] = v2;
                xp[xbase + (long long)(r + 24) * FD] = v3;
            }
            mx = fmaxf(mx, v0); sm += v0;
            mx = fmaxf(mx, v1); sm += v1;
            mx = fmaxf(mx, v2); sm += v2;
            mx = fmaxf(mx, v3); sm += v3;
        }
        for (; r < k; r += 8) {
            float v = hout[hbase + (long long)sidx[r] * FD] * skey[r];
            if (mode != 2) xp[xbase + (long long)r * FD] = v;
            mx = fmaxf(mx, v); sm += v;
        }
    }
    pmax[tid] = mx; psum[tid] = sm;
    __syncthreads();
    if (tid < 128) {
        float m = -INFINITY, su = 0.0f;
#pragma unroll
        for (int i = 0; i < 8; i++) {
            m = fmaxf(m, pmax[i * 128 + tid]);
            su += psum[i * 128 + tid];
        }
        float mean = su / (float)k;
        if (mode == 0)      { z[b * 256 + tid] = m;  z[b * 256 + 128 + tid] = mean;  }
        else if (mode == 1) { z[b * 256 + tid] += m; z[b * 256 + 128 + tid] += mean; }
        else {
            zs[tid]       = z[b * 256 + tid] + m;
            zs[128 + tid] = z[b * 256 + 128 + tid] + mean;
        }
    }
    if (mode == 2) {
        __syncthreads();
        if (tid < 128) {
            float a = b1[tid];
            for (int kk = 0; kk < 256; kk++) a += zs[kk] * W1[kk * 128 + tid];
            t1[tid] = fmaxf(a, 0.0f);
        }
        __syncthreads();
        if (tid < 64) {
            float a = b2[tid];
            for (int kk = 0; kk < 128; kk++) a += t1[kk] * W2[kk * 64 + tid];
            t2[tid] = fmaxf(a, 0.0f);
        }
        __syncthreads();
        if (tid < 10) {
            float a = b3[tid];
            for (int kk = 0; kk < 64; kk++) a += t2[kk] * W3[kk * 10 + tid];
            t3[tid] = a;
        }
        __syncthreads();
        if (tid == 0) {
            float m = -INFINITY;
            for (int i = 0; i < 10; i++) m = fmaxf(m, t3[i]);
            float su = 0.0f;
            for (int i = 0; i < 10; i++) su += expf(t3[i] - m);
            float ls = logf(su);
            for (int i = 0; i < 10; i++) out[b * 10 + i] = t3[i] - m - ls;
        }
    }
}

extern "C" void kernel_launch(void* const* d_in, const int* in_sizes, int n_in,
                              void* d_out, int out_size, void* d_ws, size_t ws_size,
                              hipStream_t stream) {
    (void)in_sizes; (void)n_in; (void)out_size; (void)ws_size;
    const float* x   = (const float*)d_in[0];
    const int*   ei  = (const int*)d_in[1];
    const float* Wl1 = (const float*)d_in[2];
    const float* bl1 = (const float*)d_in[3];
    const float* Wr1 = (const float*)d_in[4];
    const float* Wl2 = (const float*)d_in[5];
    const float* bl2 = (const float*)d_in[6];
    const float* Wr2 = (const float*)d_in[7];
    const float* Wl3 = (const float*)d_in[8];
    const float* bl3 = (const float*)d_in[9];
    const float* Wr3 = (const float*)d_in[10];
    const float* pw1 = (const float*)d_in[11];
    const float* pw2 = (const float*)d_in[12];
    const float* pw3 = (const float*)d_in[13];
    const float* W1  = (const float*)d_in[14];
    const float* b1  = (const float*)d_in[15];
    const float* W2  = (const float*)d_in[16];
    const float* b2  = (const float*)d_in[17];
    const float* W3  = (const float*)d_in[18];
    const float* b3  = (const float*)d_in[19];
    float* out = (float*)d_out;

    // workspace layout
    char* ws = (char*)d_ws;
    size_t off = 0;
    auto alloc = [&](size_t bytes) {
        char* p = ws + off;
        off = (off + bytes + 255) & ~(size_t)255;
        return p;
    };
    float* mean  = (float*)alloc((size_t)NN * FD * 4);
    float* hout  = (float*)alloc((size_t)NN * FD * 4);
    float* xp    = (float*)alloc((size_t)BG * K1 * FD * 4);
    float* sc    = (float*)alloc((size_t)NN * 4);
    int*   gmap  = (int*)  alloc((size_t)NN * 4);
    int*   deg   = (int*)  alloc((size_t)NN * 4);
    int*   colb  = (int*)  alloc((size_t)NN * CAP * 4);   // 12.8 MB
    float* z     = (float*)alloc((size_t)BG * 256 * 4);
    unsigned short* wt_hi = (unsigned short*)alloc((size_t)3 * 32768 * 2);
    unsigned short* wt_lo = (unsigned short*)alloc((size_t)3 * 32768 * 2);

    // ================= prep (CSR build + W conversion, one launch) =================
    prep_fill_kernel<<<BG + 96, 1024, 0, stream>>>(ei, deg, colb,
                                                   Wl1, Wr1, Wl2, Wr2, Wl3, Wr3, wt_hi, wt_lo);

    // ================= layer 1 =================
    {
        int nb = (NN * 32 + 255) / 256;
        gather_agg_kernel<<<nb, 256, 0, stream>>>(deg, colb, x, mean, NN, nb);
    }
    {
        int nb = (NN + 127) / 128;
        sage_gemm_mfma_kernel<<<nb, 512, 0, stream>>>(mean, x, wt_hi, wt_lo,
                                                      bl1, pw1, hout, sc, NN, nb);
    }
    topk_tail_kernel<<<2 * BG, 1024, 0, stream>>>(sc, hout, NPG, K1, 512, xp,
                                                  ei, ei + EE, gmap, deg, colb,
                                                  z, 0, W1, b1, W2, b2, W3, b3, out);

    // ================= layer 2 =================
    const int N2 = BG * K1;   // 25000
    {
        int nb = (N2 * 32 + 255) / 256;
        gather_agg_kernel<<<nb, 256, 0, stream>>>(deg, colb, xp, mean, N2, nb);
    }
    {
        int nb = (N2 + 127) / 128;
        sage_gemm_mfma_kernel<<<nb, 512, 0, stream>>>(mean, xp, wt_hi + 32768, wt_lo + 32768,
                                                      bl2, pw2, hout, sc, N2, nb);
    }
    topk_tail_kernel<<<2 * BG, 1024, 0, stream>>>(sc, hout, K1, K2, 256, xp,
                                                  ei, ei + EE, gmap, deg, colb,
                                                  z, 1, W1, b1, W2, b2, W3, b3, out);

    // ================= layer 3 =================
    const int N3 = BG * K2;   // 12500
    {
        int nb = (N3 * 32 + 255) / 256;
        gather_agg_kernel<<<nb, 256, 0, stream>>>(deg, colb, xp, mean, N3, nb);
    }
    {
        int nb = (N3 + 127) / 128;
        sage_gemm_mfma_kernel<<<nb, 512, 0, stream>>>(mean, xp, wt_hi + 65536, wt_lo + 65536,
                                                      bl3, pw3, hout, sc, N3, nb);
    }
    topk_tail_kernel<<<BG, 1024, 0, stream>>>(sc, hout, K2, K3, 128, (float*)0,
                                              (const int*)0, (const int*)0, (int*)0,
                                              (int*)0, (int*)0,
                                              z, 2, W1, b1, W2, b2, W3, b3, out);
}